// Round 3
// baseline (472.888 us; speedup 1.0000x reference)
//
#include <hip/hip_runtime.h>
#include <stdint.h>

// Problem constants: B=4096, K=128, D=512, V=128000, sparse=1 always.
// out[b,k] = dot(weight[indices[b,k]], inp[b]) + bias[indices[b,k]]
//
// v-sorted gather strategy:
//   The expensive operand is weight (262 MB, gathered 1.07 GB demand, random).
//   inp is only 8 MB (L2/L3-resident). So sort the (b,k) pairs by weight row v
//   (counting sort: histogram -> scan -> scatter), then stream weight rows
//   sequentially ONCE each (one wave per row, row held in registers) and gather
//   the cheap inp rows per pair. Weight HBM traffic: ~557 MB random -> ~258 MB
//   sequential.

constexpr int Kc = 128;
constexpr int Dc = 512;
constexpr int Vc = 128000;

// ---------------------------------------------------------------------------
// Fallback kernel (previous best, verified): one block per sample b.
// ---------------------------------------------------------------------------
__global__ __launch_bounds__(256) void SparseProjection_kernel(
    const float* __restrict__ inp,      // [B, D]
    const int*   __restrict__ indices,  // [B, K]
    const float* __restrict__ weight,   // [V, D]
    const float* __restrict__ bias,     // [V]
    float*       __restrict__ out)      // [B, K]
{
    const int b    = blockIdx.x;
    const int tid  = threadIdx.x;
    const int lane = tid & 63;
    const int wave = tid >> 6;   // 0..3

    const float4* inp_row = (const float4*)(inp + (size_t)b * Dc);
    const float4 a0 = inp_row[lane];
    const float4 a1 = inp_row[64 + lane];

    const int* idx_base  = indices + (size_t)b * Kc;
    float*     out_base  = out     + (size_t)b * Kc;

    #pragma unroll 4
    for (int i = 0; i < 32; ++i) {
        const int k   = wave * 32 + i;
        const int idx = idx_base[k];
        const float4* wrow = (const float4*)(weight + (size_t)idx * Dc);

        const float4 w0 = wrow[lane];
        const float4 w1 = wrow[64 + lane];

        float s = a0.x * w0.x + a0.y * w0.y + a0.z * w0.z + a0.w * w0.w
                + a1.x * w1.x + a1.y * w1.y + a1.z * w1.z + a1.w * w1.w;

        #pragma unroll
        for (int off = 32; off > 0; off >>= 1)
            s += __shfl_xor(s, off, 64);

        if (lane == 0)
            out_base[k] = s + bias[idx];
    }
}

// ---------------------------------------------------------------------------
// Sort pipeline
// ---------------------------------------------------------------------------

// 1) histogram of indices into counts[Vc]
__global__ __launch_bounds__(256) void hist_kernel(
    const int* __restrict__ idx, unsigned int* __restrict__ counts, int n)
{
    int i      = blockIdx.x * blockDim.x + threadIdx.x;
    int stride = gridDim.x * blockDim.x;
    for (; i < n; i += stride)
        atomicAdd(&counts[idx[i]], 1u);
}

// 2a) per-chunk sums. CHUNK=512, 250 blocks cover Vc=128000.
__global__ __launch_bounds__(256) void scan1_kernel(
    const unsigned int* __restrict__ counts, unsigned int* __restrict__ partials)
{
    __shared__ unsigned int sm[256];
    const int c = blockIdx.x;
    const int t = threadIdx.x;
    unsigned int a = counts[c * 512 + 2 * t] + counts[c * 512 + 2 * t + 1];
    sm[t] = a;
    __syncthreads();
    for (int off = 128; off > 0; off >>= 1) {
        if (t < off) sm[t] += sm[t + off];
        __syncthreads();
    }
    if (t == 0) partials[c] = sm[0];
}

// 2b) exclusive scan of the 250 partials (single block).
__global__ __launch_bounds__(256) void scan2_kernel(
    unsigned int* __restrict__ partials, int nch)
{
    __shared__ unsigned int sm[256];
    const int t = threadIdx.x;
    unsigned int v = (t < nch) ? partials[t] : 0u;
    sm[t] = v;
    __syncthreads();
    for (int off = 1; off < 256; off <<= 1) {
        unsigned int add = (t >= off) ? sm[t - off] : 0u;
        __syncthreads();
        sm[t] += add;
        __syncthreads();
    }
    if (t < nch) partials[t] = sm[t] - v;   // exclusive
}

// 2c) exclusive scan within each chunk + chunk base; writes starts[] and
//     initializes cursor[] (in-place over counts).
__global__ __launch_bounds__(256) void scan3_kernel(
    unsigned int* __restrict__ counts,          // becomes cursor
    const unsigned int* __restrict__ partials,
    unsigned int* __restrict__ starts,
    int n_total)
{
    __shared__ unsigned int sm[256];
    const int c    = blockIdx.x;
    const int t    = threadIdx.x;
    const int base = c * 512;
    unsigned int c0 = counts[base + 2 * t];
    unsigned int c1 = counts[base + 2 * t + 1];
    unsigned int pair = c0 + c1;
    sm[t] = pair;
    __syncthreads();
    for (int off = 1; off < 256; off <<= 1) {
        unsigned int add = (t >= off) ? sm[t - off] : 0u;
        __syncthreads();
        sm[t] += add;
        __syncthreads();
    }
    unsigned int excl = sm[t] - pair + partials[c];
    unsigned int s0 = excl;
    unsigned int s1 = excl + c0;
    starts[base + 2 * t]     = s0;
    starts[base + 2 * t + 1] = s1;
    counts[base + 2 * t]     = s0;   // cursor init
    counts[base + 2 * t + 1] = s1;
    if (c == 0 && t == 0) starts[Vc] = (unsigned int)n_total;
}

// 3) scatter pair ids into v-sorted order
__global__ __launch_bounds__(256) void scatter_kernel(
    const int* __restrict__ idx, unsigned int* __restrict__ cursor,
    unsigned int* __restrict__ sorted, int n)
{
    int i      = blockIdx.x * blockDim.x + threadIdx.x;
    int stride = gridDim.x * blockDim.x;
    for (; i < n; i += stride) {
        int v = idx[i];
        unsigned int pos = atomicAdd(&cursor[v], 1u);
        sorted[pos] = (unsigned int)i;
    }
}

// ---------------------------------------------------------------------------
// 4) compute: one wave per weight row v. Row (2KB) lives in registers; loop
//    over this row's (b,k) pairs gathering the (cache-resident) inp rows.
// ---------------------------------------------------------------------------
__global__ __launch_bounds__(256) void compute_sorted_kernel(
    const float* __restrict__ inp,            // [B, D]
    const float* __restrict__ weight,         // [V, D]
    const float* __restrict__ bias,           // [V]
    const unsigned int* __restrict__ starts,  // [V+1]
    const unsigned int* __restrict__ sorted,  // [B*K] pair ids b*K+k
    float* __restrict__ out)                  // [B, K]
{
    const int lane = threadIdx.x & 63;
    const int wave = threadIdx.x >> 6;
    const int v    = blockIdx.x * 4 + wave;

    const unsigned int s = starts[v];
    const unsigned int e = starts[v + 1];
    if (s == e) return;   // untouched row: skip entirely (no weight read)

    const float4* wrow = (const float4*)(weight + (size_t)v * Dc);
    const float4 w0 = wrow[lane];
    const float4 w1 = wrow[64 + lane];
    const float  bv = bias[v];

    for (unsigned int j = s; j < e; ++j) {
        const unsigned int bk = sorted[j];
        const float4* arow = (const float4*)(inp + (size_t)(bk >> 7) * Dc);
        const float4 a0 = arow[lane];
        const float4 a1 = arow[64 + lane];

        float sdot = a0.x * w0.x + a0.y * w0.y + a0.z * w0.z + a0.w * w0.w
                   + a1.x * w1.x + a1.y * w1.y + a1.z * w1.z + a1.w * w1.w;

        #pragma unroll
        for (int off = 32; off > 0; off >>= 1)
            sdot += __shfl_xor(sdot, off, 64);

        if (lane == 0)
            out[bk] = sdot + bv;
    }
}

// ---------------------------------------------------------------------------
extern "C" void kernel_launch(void* const* d_in, const int* in_sizes, int n_in,
                              void* d_out, int out_size, void* d_ws, size_t ws_size,
                              hipStream_t stream) {
    const float* inp     = (const float*)d_in[0];   // [B, 512] f32
    const int*   indices = (const int*)  d_in[1];   // [B, 128] int32 (verified)
    // d_in[2] = sparse flag (always 1) -- dense branch is dead code.
    const float* weight  = (const float*)d_in[3];   // [128000, 512] f32
    const float* bias    = (const float*)d_in[4];   // [128000] f32
    float*       out     = (float*)d_out;           // [B, 128] f32

    const int B = in_sizes[0] / Dc;                 // 4096
    const int n = B * Kc;                           // 524288 pairs

    // ws layout (uint32):
    //   [0, Vc)                 counts -> cursor
    //   [Vc, 2Vc+1)             starts
    //   [2Vc+64, 2Vc+64+n)      sorted pair ids
    //   [2Vc+64+n, +256)        scan partials
    const size_t need_u32 = (size_t)2 * Vc + 64 + (size_t)n + 256;
    if (ws_size < need_u32 * sizeof(unsigned int)) {
        // Workspace too small: fall back to verified per-sample kernel.
        SparseProjection_kernel<<<B, 256, 0, stream>>>(inp, indices, weight, bias, out);
        return;
    }

    unsigned int* ws       = (unsigned int*)d_ws;
    unsigned int* counts   = ws;                       // Vc (becomes cursor)
    unsigned int* starts   = ws + Vc;                  // Vc+1
    unsigned int* sorted   = ws + 2 * Vc + 64;         // n
    unsigned int* partials = sorted + n;               // 256

    hipMemsetAsync(counts, 0, (size_t)Vc * sizeof(unsigned int), stream);

    hist_kernel<<<2048, 256, 0, stream>>>(indices, counts, n);
    scan1_kernel<<<Vc / 512, 256, 0, stream>>>(counts, partials);
    scan2_kernel<<<1, 256, 0, stream>>>(partials, Vc / 512);
    scan3_kernel<<<Vc / 512, 256, 0, stream>>>(counts, partials, starts, n);
    scatter_kernel<<<2048, 256, 0, stream>>>(indices, counts, sorted, n);

    compute_sorted_kernel<<<Vc / 4, 256, 0, stream>>>(inp, weight, bias, starts, sorted, out);
}